// Round 1
// baseline (161.243 us; speedup 1.0000x reference)
//
#include <hip/hip_runtime.h>
#include <cstdint>
#include <cstddef>

namespace {

constexpr int NCLS   = 32;      // N classes
constexpr int KSHOT  = 5;
constexpr int FDIM   = 21168;   // 3*84*84
constexpr int KPAD   = 21248;   // 332 * 64 (zero-padded K)
constexpr int DDIM   = 1600;
constexpr int NROW   = 512;     // 32 proto rows + 480 query rows
constexpr int NQROW  = 480;
constexpr int NKT    = 332;     // K tiles of 64
constexpr int SPLITK = 16;
constexpr int CHUNK  = 21;      // ceil(332/16)

using short8 = __attribute__((ext_vector_type(8))) short;
using f32x4  = __attribute__((ext_vector_type(4))) float;

__device__ __forceinline__ unsigned short f2bf(float x) {
    union { float f; unsigned u; } v; v.f = x;
    unsigned r = v.u + 0x7fffu + ((v.u >> 16) & 1u);   // round-to-nearest-even
    return (unsigned short)(r >> 16);
}

// ---------------------------------------------------------------------------
// Kernel 1: build A_bf16 [512][KPAD]: rows 0..31 = mean over 5 shots of supp,
// rows 32..511 = query rows. K zero-padded to KPAD.
// ---------------------------------------------------------------------------
__global__ void prep_A(const float* __restrict__ supp,
                       const float* __restrict__ query,
                       unsigned short* __restrict__ A) {
    const int units = NROW * (KPAD / 4);
    for (int u = blockIdx.x * blockDim.x + threadIdx.x; u < units;
         u += gridDim.x * blockDim.x) {
        const int r = u / (KPAD / 4);
        const int c = (u % (KPAD / 4)) * 4;
        float4 v = make_float4(0.f, 0.f, 0.f, 0.f);
        if (c < FDIM) {   // FDIM % 4 == 0, so full vec is in-range
            if (r < NCLS) {
                const float* s = supp + (size_t)r * KSHOT * FDIM + c;
                float4 a0 = *(const float4*)(s);
                float4 a1 = *(const float4*)(s + FDIM);
                float4 a2 = *(const float4*)(s + 2 * FDIM);
                float4 a3 = *(const float4*)(s + 3 * FDIM);
                float4 a4 = *(const float4*)(s + 4 * FDIM);
                v.x = (a0.x + a1.x + a2.x + a3.x + a4.x) * 0.2f;
                v.y = (a0.y + a1.y + a2.y + a3.y + a4.y) * 0.2f;
                v.z = (a0.z + a1.z + a2.z + a3.z + a4.z) * 0.2f;
                v.w = (a0.w + a1.w + a2.w + a3.w + a4.w) * 0.2f;
            } else {
                v = *(const float4*)(query + (size_t)(r - NCLS) * FDIM + c);
            }
        }
        ushort4 o;
        o.x = f2bf(v.x); o.y = f2bf(v.y); o.z = f2bf(v.z); o.w = f2bf(v.w);
        *(ushort4*)(A + (size_t)r * KPAD + c) = o;
    }
}

// ---------------------------------------------------------------------------
// Kernel 2: GEMM  C[512][1600] = A_bf16 @ bf16(W).   BM=256 BN=128 BK=64,
// 512 threads = 8 waves (4 m-waves x 2 n-waves), wave tile 64x64,
// split-K=16 -> partial buffers (deterministic reduce later).
// A: global_load_lds (16B) with XOR-preswizzled global source.
// B: fp32 read, cvt to bf16, stored transposed [n][64+8] (pad kills conflicts).
// ---------------------------------------------------------------------------
__global__ __launch_bounds__(512, 4) void gemm_kernel(
        const unsigned short* __restrict__ A,   // [512][KPAD] bf16 bits
        const float* __restrict__ W,            // [FDIM][DDIM] fp32
        float* __restrict__ Cpart) {            // [SPLITK][512][DDIM]
    __shared__ unsigned short Al[256 * 64];     // linear (content XOR-swizzled)
    __shared__ unsigned short Bl[128 * 72];     // [n][72] (k-major, +8 pad)

    const int b   = blockIdx.x;
    const int s   = b / 26;                     // split index
    const int rem = b % 26;
    const int mt  = rem / 13;
    const int nt  = rem % 13;
    const int m0  = mt * 256;
    const int n0  = nt * 128;
    const int t0  = s * CHUNK;
    const int t1  = min(NKT, t0 + CHUNK);

    const int tid  = threadIdx.x;
    const int lane = tid & 63;
    const int wid  = tid >> 6;                  // 0..7
    const int wr   = wid >> 1;                  // 0..3 (m)
    const int wc   = wid & 1;                   // 0..1 (n)

    // B staging assignment: n = tid&127, k-quarter = tid>>7
    const int bn = tid & 127;
    const int bw = tid >> 7;                    // 0..3
    const int ncol = n0 + bn;
    const bool nok = ncol < DDIM;

    const int arow_in_chunk = lane >> 3;        // 0..7
    const int ablk = lane & 7;

    f32x4 acc[4][4];
    #pragma unroll
    for (int i = 0; i < 4; ++i)
        #pragma unroll
        for (int j = 0; j < 4; ++j)
            acc[i][j] = (f32x4){0.f, 0.f, 0.f, 0.f};

    for (int t = t0; t < t1; ++t) {
        const int k0 = t * 64;
        // ---- A stage: 4 x global_load_lds(16B) per wave, 8 rows per issue
        #pragma unroll
        for (int i = 0; i < 4; ++i) {
            const int rowbase = (wid * 4 + i) * 8;
            const int row = rowbase + arow_in_chunk;
            const int d = ablk ^ (row & 7);     // pre-swizzled source block
            const unsigned short* src =
                A + (size_t)(m0 + row) * KPAD + k0 + d * 8;
            unsigned short* dst = &Al[rowbase * 64];
            __builtin_amdgcn_global_load_lds(
                (const __attribute__((address_space(1))) void*)src,
                (__attribute__((address_space(3))) void*)dst, 16, 0, 0);
        }
        // ---- B stage: 16 scalar fp32 loads -> bf16 -> 2 x ds_write_b128
        #pragma unroll
        for (int half = 0; half < 2; ++half) {
            const int kb = k0 + bw * 16 + half * 8;
            unsigned short h[8];
            #pragma unroll
            for (int i = 0; i < 8; ++i) {
                const int kg = kb + i;
                float v = (nok && kg < FDIM) ? W[(size_t)kg * DDIM + ncol] : 0.f;
                h[i] = f2bf(v);
            }
            uint4 pk;
            pk.x = (unsigned)h[0] | ((unsigned)h[1] << 16);
            pk.y = (unsigned)h[2] | ((unsigned)h[3] << 16);
            pk.z = (unsigned)h[4] | ((unsigned)h[5] << 16);
            pk.w = (unsigned)h[6] | ((unsigned)h[7] << 16);
            *(uint4*)(&Bl[bn * 72 + bw * 16 + half * 8]) = pk;
        }
        __syncthreads();
        // ---- compute: 2 k-halves x (4m x 4n) MFMAs
        #pragma unroll
        for (int kk = 0; kk < 2; ++kk) {
            short8 af[4], bfr[4];
            #pragma unroll
            for (int ms = 0; ms < 4; ++ms) {
                const int R = wr * 64 + ms * 16 + (lane & 15);
                const int dd = kk * 4 + (lane >> 4);
                const int pos = dd ^ (R & 7);
                af[ms] = *(const short8*)(&Al[R * 64 + pos * 8]);
            }
            #pragma unroll
            for (int ns = 0; ns < 4; ++ns) {
                const int Rn = wc * 64 + ns * 16 + (lane & 15);
                bfr[ns] = *(const short8*)(&Bl[Rn * 72 + kk * 32 + (lane >> 4) * 8]);
            }
            #pragma unroll
            for (int ms = 0; ms < 4; ++ms)
                #pragma unroll
                for (int ns = 0; ns < 4; ++ns)
                    acc[ms][ns] = __builtin_amdgcn_mfma_f32_16x16x32_bf16(
                        af[ms], bfr[ns], acc[ms][ns], 0, 0, 0);
        }
        __syncthreads();
    }

    // ---- epilogue: write split partial (plain stores, deterministic)
    float* Cp = Cpart + (size_t)s * NROW * DDIM;
    #pragma unroll
    for (int ms = 0; ms < 4; ++ms) {
        const int row = m0 + wr * 64 + ms * 16 + ((lane >> 4) * 4);
        #pragma unroll
        for (int ns = 0; ns < 4; ++ns) {
            const int col = n0 + wc * 64 + ns * 16 + (lane & 15);
            if (col < DDIM) {
                #pragma unroll
                for (int r = 0; r < 4; ++r)
                    Cp[(size_t)(row + r) * DDIM + col] = acc[ms][ns][r];
            }
        }
    }
}

// ---------------------------------------------------------------------------
// Kernel 3: sum the 16 split partials -> C, plus per-row inverse norm.
// One block per row.
// ---------------------------------------------------------------------------
__global__ void reduce_norm(const float* __restrict__ Cpart,
                            float* __restrict__ C,
                            float* __restrict__ inv_norm) {
    const int row = blockIdx.x;
    const int tid = threadIdx.x;
    float acc = 0.f;
    for (int c = tid; c < DDIM; c += 256) {
        float v = 0.f;
        #pragma unroll
        for (int s2 = 0; s2 < SPLITK; ++s2)
            v += Cpart[(size_t)s2 * NROW * DDIM + (size_t)row * DDIM + c];
        C[(size_t)row * DDIM + c] = v;
        acc += v * v;
    }
    __shared__ float red[4];
    #pragma unroll
    for (int off = 32; off > 0; off >>= 1) acc += __shfl_xor(acc, off);
    if ((tid & 63) == 0) red[tid >> 6] = acc;
    __syncthreads();
    if (tid == 0) {
        float a = red[0] + red[1] + red[2] + red[3];
        inv_norm[row] = 1.f / fmaxf(sqrtf(a), 1e-8f);
    }
}

// ---------------------------------------------------------------------------
// Kernel 4: fused cosine-sim (480x32) + log_softmax. One block per query row.
// ---------------------------------------------------------------------------
__global__ void simlog(const float* __restrict__ C,
                       const float* __restrict__ inv_norm,
                       float* __restrict__ out) {
    __shared__ float qs[DDIM];
    __shared__ float sims[NCLS];
    const int r = blockIdx.x;          // query row 0..479
    const int tid = threadIdx.x;
    const float* qrow = C + (size_t)(NCLS + r) * DDIM;
    for (int c = tid; c < DDIM; c += 256) qs[c] = qrow[c];
    __syncthreads();
    const float invq = inv_norm[NCLS + r];
    const int lane = tid & 63, w = tid >> 6;
    #pragma unroll
    for (int j = 0; j < 8; ++j) {
        const int p = w * 8 + j;
        const float* prow = C + (size_t)p * DDIM;
        float d = 0.f;
        for (int c = lane; c < DDIM; c += 64) d += qs[c] * prow[c];
        #pragma unroll
        for (int off = 32; off > 0; off >>= 1) d += __shfl_xor(d, off);
        if (lane == 0) sims[p] = d * invq * inv_norm[p];
    }
    __syncthreads();
    if (w == 0) {
        float v = (lane < NCLS) ? sims[lane] : -1e30f;
        float m = v;
        #pragma unroll
        for (int off = 32; off > 0; off >>= 1) m = fmaxf(m, __shfl_xor(m, off));
        float e = (lane < NCLS) ? expf(v - m) : 0.f;
        float ss = e;
        #pragma unroll
        for (int off = 32; off > 0; off >>= 1) ss += __shfl_xor(ss, off);
        if (lane < NCLS) out[(size_t)r * NCLS + lane] = v - m - logf(ss);
    }
}

} // anonymous namespace

// ws layout (bytes):
//   A_bf16 : [0, 21,757,952)                      512*21248*2
//   Cpart  : [21,757,952, +52,428,800)            16*512*1600*4
//   C      : [74,186,752, +3,276,800)             512*1600*4
//   invn   : [77,463,552, +2,048)                 512*4
// total ~77.5 MB

extern "C" void kernel_launch(void* const* d_in, const int* in_sizes, int n_in,
                              void* d_out, int out_size, void* d_ws, size_t ws_size,
                              hipStream_t stream) {
    const float* supp  = (const float*)d_in[0];
    const float* query = (const float*)d_in[1];
    const float* Wenc  = (const float*)d_in[2];
    float* out = (float*)d_out;

    char* ws = (char*)d_ws;
    unsigned short* A = (unsigned short*)ws;
    float* Cpart     = (float*)(ws + 21757952);
    float* C         = (float*)(ws + 21757952 + 52428800);
    float* inv_norm  = (float*)(ws + 21757952 + 52428800 + 3276800);

    hipLaunchKernelGGL(prep_A, dim3(2048), dim3(256), 0, stream, supp, query, A);
    hipLaunchKernelGGL(gemm_kernel, dim3(SPLITK * 26), dim3(512), 0, stream,
                       A, Wenc, Cpart);
    hipLaunchKernelGGL(reduce_norm, dim3(NROW), dim3(256), 0, stream,
                       Cpart, C, inv_norm);
    hipLaunchKernelGGL(simlog, dim3(NQROW), dim3(256), 0, stream,
                       C, inv_norm, out);
}